// Round 8
// baseline (35.365 us; speedup 1.0000x reference)
//
#include <hip/hip_runtime.h>
#include <hip/hip_bf16.h>

#define LOG2E 1.44269504088896340736f
#define C2G   0.39894228040143267794f   // 1/sqrt(2*pi)
#define K2M  -0.79788456080286535588f   // -2*C2G

typedef __attribute__((ext_vector_type(4))) float f32x4;
typedef __attribute__((ext_vector_type(8))) short s16x8;
typedef __attribute__((ext_vector_type(4))) short s16x4;

// ---------------- workspace layout (float offsets) ----------------
static constexpr size_t QF_OFF   = 0;        // [4h][64nt][2s][64l][8j] bf16
static constexpr size_t KF_OFF   = 131072;   // same shape (m-tiles)
static constexpr size_t VF_OFF   = 262144;   // [32ks][8tc][64l][8j] bf16
static constexpr size_t WoF_OFF  = 327680;   // [8ot][4s][64l][8j]  bf16
static constexpr size_t PACC_OFF = 335872;   // bf16 [8 chunk][128 c][1024 n]
static constexpr size_t PMAX_OFF = 860160;   // [8][4][1024] fp32
static constexpr size_t PSUM_OFF = 892928;   // [8][4][1024] fp32
// total = 925,696 floats = 3.53 MB

__device__ __forceinline__ short f2bfs(float f){
    __hip_bfloat16 h = __float2bfloat16(f);
    return __builtin_bit_cast(short, h);
}
__device__ __forceinline__ float bf2f(short u){
    return __builtin_bit_cast(float, ((unsigned)(unsigned short)u) << 16);
}
__device__ __forceinline__ float wave_sum64(float v){
    #pragma unroll
    for (int m = 32; m >= 1; m >>= 1) v += __shfl_xor(v, m, 64);
    return v;
}

// ---------------- kernel 1: MFMA projections + pos terms -> fragments ----
// grid (64, 2): x = n-tile of 16; y=0: Q/K/V via MFMA, y=1: pos terms + WoF.
// k-bijections (A and B share the map; HW-validated R5-R7):
//   scores g(l,j) = (l>>4)*8 + j
//   PV/Wo  f(l,j) = (l>>4)*4 + (j&3) + 16*(j>>2)
__global__ __launch_bounds__(256) void k_prep(
    const float* __restrict__ x, const float* __restrict__ xyz,
    const float* __restrict__ Wq, const float* __restrict__ Wk,
    const float* __restrict__ Wv, const float* __restrict__ Wp1,
    const float* __restrict__ bp1, const float* __restrict__ Wp2,
    const float* __restrict__ bp2, const float* __restrict__ Wo,
    float* __restrict__ ws)
{
    __shared__ float stQ[128*17];   // [c][n] pitch 17 (y=1: p-tile)
    __shared__ float stK[128*17];   // (y=1: scratch)
    __shared__ float stV[128*17];
    const int t  = threadIdx.x;
    const int bx = blockIdx.x;
    const int n0 = bx * 16;
    const int l = t & 63, w = t >> 6, g = l >> 4, col = l & 15;

    if (blockIdx.y == 0){
        // ---- B-frags: x-tile bf16 ----
        s16x8 xb[4];
        #pragma unroll
        for (int s = 0; s < 4; s++){
            s16x8 v;
            #pragma unroll
            for (int j = 0; j < 8; j++)
                v[j] = f2bfs(x[(size_t)(s*32 + g*8 + j)*1024 + n0 + col]);
            xb[s] = v;
        }
        // ---- 3 projections via MFMA; wave handles mtiles {2w, 2w+1} ----
        auto do_mat = [&](const float* __restrict__ W, float* stg, float scale){
            #pragma unroll
            for (int q = 0; q < 2; q++){
                const int mt = w*2 + q;
                f32x4 acc = {0.f,0.f,0.f,0.f};
                #pragma unroll
                for (int s = 0; s < 4; s++){
                    const float* wp = W + (size_t)(mt*16 + col)*128 + s*32 + g*8;
                    const float4 w0 = *(const float4*)wp;
                    const float4 w1 = *(const float4*)(wp + 4);
                    s16x8 a;
                    a[0]=f2bfs(w0.x); a[1]=f2bfs(w0.y); a[2]=f2bfs(w0.z); a[3]=f2bfs(w0.w);
                    a[4]=f2bfs(w1.x); a[5]=f2bfs(w1.y); a[6]=f2bfs(w1.z); a[7]=f2bfs(w1.w);
                    acc = __builtin_amdgcn_mfma_f32_16x16x32_bf16(a, xb[s], acc, 0, 0, 0);
                }
                #pragma unroll
                for (int r = 0; r < 4; r++)
                    stg[(mt*16 + g*4 + r)*17 + col] = acc[r]*scale;
            }
        };
        do_mat(Wq, stQ, 0.17677669529663689f);   // 1/sqrt(32)
        do_mat(Wk, stK, 1.0f);
        do_mat(Wv, stV, 1.0f);
        __syncthreads();

        // ---- emit fragments (layouts identical to R7) ----
        {   // QF s=0, wave = head
            s16x8 v;
            #pragma unroll
            for (int j = 0; j < 8; j++)
                v[j] = f2bfs(stQ[(w*32 + g*8 + j)*17 + col]);
            ((s16x8*)(ws + QF_OFF))[(size_t)(w*128 + bx*2 + 0)*64 + l] = v;
        }
        {   // KF s=0
            s16x8 v;
            #pragma unroll
            for (int j = 0; j < 8; j++)
                v[j] = f2bfs(stK[(w*32 + g*8 + j)*17 + col]);
            ((s16x8*)(ws + KF_OFF))[(size_t)(w*128 + bx*2 + 0)*64 + l] = v;
        }
        #pragma unroll
        for (int q = 0; q < 2; q++){   // V half-fragments (this block = m-tile bx)
            const int tc = w*2 + q;
            s16x4 hv;
            #pragma unroll
            for (int jj = 0; jj < 4; jj++)
                hv[jj] = f2bfs(stV[(tc*16 + col)*17 + g*4 + jj]);
            ((s16x4*)(ws + VF_OFF))[(((size_t)(bx>>1)*8 + tc)*64 + l)*2 + (bx & 1)] = hv;
        }
        return;
    }

    // ================= y == 1: pos terms + WoF =================
    // WoF: blocks bx<8, one slot per wave. slot = ot*4 + s. (R6-validated)
    if (bx < 8){
        const int slot = bx*4 + w;
        const int ot = slot >> 2, s = slot & 3;
        s16x8 v;
        #pragma unroll
        for (int j = 0; j < 8; j++)
            v[j] = f2bfs(Wo[(size_t)(ot*16 + col)*128
                           + s*32 + g*4 + (j&3) + 16*(j>>2)]);
        ((s16x8*)(ws + WoF_OFF))[(size_t)slot*64 + l] = v;
    }

    float* pt   = stQ;          // [128][17]
    float* wb   = stK;          // [4][128]
    float* Msh  = stK + 512;    // [4][9]
    float* bbar = stK + 548;    // [4]
    float* kg   = stK + 552;    // [4][3][16]
    float* rowt = stK + 744;    // [4][16]
    float* colt = stK + 808;    // [4][16]

    for (int idx = t; idx < 512; idx += 256){
        const int h = idx >> 7, c = idx & 127;
        float s = 0.f;
        #pragma unroll 8
        for (int d = 0; d < 32; d++) s += Wp2[(size_t)(h*32+d)*128 + c];
        wb[idx] = s * 0.03125f;
    }
    if (t < 4){
        float s = 0.f;
        #pragma unroll 8
        for (int d = 0; d < 32; d++) s += bp2[t*32+d];
        bbar[t] = s * 0.03125f;
    }
    {   // p-tile
        const int c = t & 127, ng = t >> 7;
        const float w0 = Wp1[c*3], w1 = Wp1[c*3+1], w2 = Wp1[c*3+2];
        #pragma unroll
        for (int i = 0; i < 8; i++){
            const int nn = ng*8 + i, n = n0 + nn;
            pt[c*17 + nn] = w0*xyz[n*3] + w1*xyz[n*3+1] + w2*xyz[n*3+2];
        }
    }
    __syncthreads();

    if (t < 36){   // M_h[a][b] = sum_c wbar * Wp1[c,a] * Wp1[c,b]
        const int h = t / 9, ab = t % 9, a = ab / 3, b = ab % 3;
        float m = 0.f;
        for (int c = 0; c < 128; c++)
            m += wb[h*128+c] * Wp1[c*3+a] * Wp1[c*3+b];
        Msh[t] = m;
    }
    __syncthreads();

    if (t < 64){   // ROWT / COLT
        const int h = t >> 4, nn = t & 15;
        float ra = 0.f, ca = 0.f;
        for (int c = 0; c < 128; c++){
            const float wv = wb[h*128+c];
            const float p  = pt[c*17+nn];
            const float b1 = bp1[c];
            const float a  = fmaf(2.f*C2G, b1, 0.5f);
            const float p2 = C2G*p*p;
            ra += wv * (a*p + p2 + 0.5f*b1 + C2G*b1*b1);
            ca += wv * (p2 - a*p);
        }
        rowt[h*16+nn] = ra + bbar[h];
        colt[h*16+nn] = ca;
    } else if (t < 64 + 192){   // kg[h][a][nn]
        const int u = t - 64;
        const int nn = u & 15, ha = u >> 4, h = ha / 3, a = ha % 3;
        const int n = n0 + nn;
        const float gv = Msh[h*9+a*3+0]*xyz[n*3+0]
                       + Msh[h*9+a*3+1]*xyz[n*3+1]
                       + Msh[h*9+a*3+2]*xyz[n*3+2];
        kg[(h*3+a)*16 + nn] = K2M * gv;
    }
    __syncthreads();

    // bias fragments (s=1) for QF and KF: 8 slots, 2 per wave
    for (int sl = w; sl < 8; sl += 4){
        const bool isQ = sl < 4;
        const int  h   = sl & 3;
        s16x8 v;
        #pragma unroll
        for (int j = 0; j < 8; j++){
            const int dd = g*8 + j;
            float f;
            if (isQ)
                f = (dd < 3)  ? kg[(h*3+dd)*16 + col]
                  : (dd == 3) ? rowt[h*16 + col]
                  : (dd == 4) ? 1.0f : 0.0f;
            else
                f = (dd < 3)  ? xyz[(size_t)(n0+col)*3 + dd]
                  : (dd == 3) ? 1.0f
                  : (dd == 4) ? colt[h*16 + col] : 0.0f;
            v[j] = f2bfs(f);
        }
        ((s16x8*)(ws + (isQ ? QF_OFF : KF_OFF)))[(size_t)(h*128 + bx*2 + 1)*64 + l] = v;
    }
}

// ---------------- kernel 2: MFMA scores + chunk softmax + MFMA PV --------
// grid (64, 8): x = n-tile of 16, y = m-chunk of 128. block 256 = 4 waves,
// wave = head. Wave h owns PV channels tc = 2h, 2h+1.
__global__ __launch_bounds__(256) void k_attn(
    const float* __restrict__ ws_c, float* __restrict__ ws)
{
    const int t = threadIdx.x, l = t & 63, h = t >> 6;
    const int bx = blockIdx.x, by = blockIdx.y;
    const int g = l >> 4;

    const s16x8* QFv = (const s16x8*)(ws_c + QF_OFF);
    const s16x8* KFv = (const s16x8*)(ws_c + KF_OFF);
    const s16x8* VFv = (const s16x8*)(ws_c + VF_OFF);

    const s16x8 bq0 = QFv[(size_t)(h*128 + bx*2 + 0)*64 + l];
    const s16x8 bq1 = QFv[(size_t)(h*128 + bx*2 + 1)*64 + l];

    f32x4 sc[8];
    #pragma unroll
    for (int tt = 0; tt < 8; tt++){
        const int mt = by*8 + tt;
        const s16x8 ak0 = KFv[(size_t)(h*128 + mt*2 + 0)*64 + l];
        const s16x8 ak1 = KFv[(size_t)(h*128 + mt*2 + 1)*64 + l];
        f32x4 c = {0.f,0.f,0.f,0.f};
        c = __builtin_amdgcn_mfma_f32_16x16x32_bf16(ak0, bq0, c, 0, 0, 0);
        c = __builtin_amdgcn_mfma_f32_16x16x32_bf16(ak1, bq1, c, 0, 0, 0);
        sc[tt] = c;
    }

    float mx = -3.4e38f;
    #pragma unroll
    for (int tt = 0; tt < 8; tt++)
        #pragma unroll
        for (int r = 0; r < 4; r++) mx = fmaxf(mx, sc[tt][r]);
    mx = fmaxf(mx, __shfl_xor(mx, 16, 64));
    mx = fmaxf(mx, __shfl_xor(mx, 32, 64));

    float sum = 0.f;
    #pragma unroll
    for (int tt = 0; tt < 8; tt++)
        #pragma unroll
        for (int r = 0; r < 4; r++){
            const float e = __builtin_amdgcn_exp2f((sc[tt][r] - mx)*LOG2E);
            sc[tt][r] = e;
            sum += e;
        }
    sum += __shfl_xor(sum, 16, 64);
    sum += __shfl_xor(sum, 32, 64);

    if (l < 16){
        ws[PMAX_OFF + (size_t)(by*4 + h)*1024 + bx*16 + l] = mx;
        ws[PSUM_OFF + (size_t)(by*4 + h)*1024 + bx*16 + l] = sum;
    }

    s16x8 pb[4];
    #pragma unroll
    for (int s = 0; s < 4; s++){
        s16x8 b;
        #pragma unroll
        for (int r = 0; r < 4; r++){
            b[r]   = f2bfs(sc[2*s][r]);
            b[4+r] = f2bfs(sc[2*s+1][r]);
        }
        pb[s] = b;
    }

    f32x4 o0 = {0.f,0.f,0.f,0.f}, o1 = {0.f,0.f,0.f,0.f};
    #pragma unroll
    for (int s = 0; s < 4; s++){
        const s16x8 av0 = VFv[(size_t)((by*4 + s)*8 + 2*h    )*64 + l];
        const s16x8 av1 = VFv[(size_t)((by*4 + s)*8 + 2*h + 1)*64 + l];
        o0 = __builtin_amdgcn_mfma_f32_16x16x32_bf16(av0, pb[s], o0, 0, 0, 0);
        o1 = __builtin_amdgcn_mfma_f32_16x16x32_bf16(av1, pb[s], o1, 0, 0, 0);
    }
    // PACC bf16 [chunk][c][n]: c = tc*16 + g*4 + r, n = bx*16 + (l&15)
    ushort* PB = (ushort*)(ws + PACC_OFF);
    const size_t cb0 = ((size_t)by*128 + 2*h*16     + g*4);
    const size_t cb1 = ((size_t)by*128 + (2*h+1)*16 + g*4);
    const int n = bx*16 + (l & 15);
    s16x4 pa0, pa1;
    #pragma unroll
    for (int r = 0; r < 4; r++){ pa0[r] = f2bfs(o0[r]); pa1[r] = f2bfs(o1[r]); }
    // scalar stores: consecutive lanes in a g-group share c, consecutive n
    #pragma unroll
    for (int r = 0; r < 4; r++){
        PB[(cb0 + r)*1024 + n] = (ushort)pa0[r];
        PB[(cb1 + r)*1024 + n] = (ushort)pa1[r];
    }
}

// ---------------- kernel 3: combine + MFMA Wo + residual + LayerNorm -----
// grid (64): n-tile of 16. block 256 = 4 waves.
__global__ __launch_bounds__(256) void k_final(
    const float* __restrict__ bo, const float* __restrict__ x,
    const float* __restrict__ gamma, const float* __restrict__ beta,
    const float* __restrict__ ws_c, float* __restrict__ out)
{
    __shared__ float wcomb[8*4*16];   // [k][h][nn]
    __shared__ float lnb[16*129];     // [nn][c] pitch 129
    __shared__ float stats[32];       // mu[16], rstd[16]
    const int t = threadIdx.x, l = t & 63, w = t >> 6, g = l >> 4, col = l & 15;
    const int bx = blockIdx.x, n0 = bx*16;

    if (t < 64){   // combine weights per (h, nn)
        const int h = t >> 4, nn = t & 15;
        float pm[8]; float mx = -3.4e38f;
        #pragma unroll
        for (int k = 0; k < 8; k++){
            pm[k] = ws_c[PMAX_OFF + (size_t)(k*4 + h)*1024 + n0 + nn];
            mx = fmaxf(mx, pm[k]);
        }
        float lam[8]; float den = 0.f;
        #pragma unroll
        for (int k = 0; k < 8; k++){
            lam[k] = __builtin_amdgcn_exp2f((pm[k] - mx)*LOG2E);
            den = fmaf(lam[k], ws_c[PSUM_OFF + (size_t)(k*4 + h)*1024 + n0 + nn], den);
        }
        const float rd = __builtin_amdgcn_rcpf(den);
        #pragma unroll
        for (int k = 0; k < 8; k++) wcomb[(k*4 + h)*16 + nn] = lam[k]*rd;
    }
    __syncthreads();

    // build AO B-frags (f-bijection: c = s*32 + g*4 + (j&3) + 16*(j>>2))
    const ushort* PB = (const ushort*)(ws_c + PACC_OFF);
    s16x8 bf[4];
    #pragma unroll
    for (int s = 0; s < 4; s++){
        s16x8 v;
        #pragma unroll
        for (int jp = 0; jp < 2; jp++){
            const int cbase = s*32 + 16*jp + g*4;
            float a0=0.f, a1=0.f, a2=0.f, a3=0.f;
            #pragma unroll
            for (int k = 0; k < 8; k++){
                const float wc = wcomb[(k*4 + s)*16 + col];
                // PACC [k][c][n]: 4 consecutive c at fixed n? No: vector over n is
                // per-lane; read 4 c's as 4 scalar ushorts at stride 1024.
                const size_t base = ((size_t)k*128 + cbase)*1024 + n0 + col;
                a0 = fmaf(wc, bf2f((short)PB[base        ]), a0);
                a1 = fmaf(wc, bf2f((short)PB[base + 1024 ]), a1);
                a2 = fmaf(wc, bf2f((short)PB[base + 2048 ]), a2);
                a3 = fmaf(wc, bf2f((short)PB[base + 3072 ]), a3);
            }
            v[jp*4+0]=f2bfs(a0); v[jp*4+1]=f2bfs(a1);
            v[jp*4+2]=f2bfs(a2); v[jp*4+3]=f2bfs(a3);
        }
        bf[s] = v;
    }

    // Wo MFMA: wave w handles ot = 2w, 2w+1
    const s16x8* WoFv = (const s16x8*)(ws_c + WoF_OFF);
    #pragma unroll
    for (int q = 0; q < 2; q++){
        const int ot = w*2 + q;
        f32x4 o = {0.f,0.f,0.f,0.f};
        #pragma unroll
        for (int s = 0; s < 4; s++)
            o = __builtin_amdgcn_mfma_f32_16x16x32_bf16(
                    WoFv[(size_t)(ot*4 + s)*64 + l], bf[s], o, 0, 0, 0);
        #pragma unroll
        for (int r = 0; r < 4; r++)
            lnb[col*129 + ot*16 + g*4 + r] = o[r];
    }
    __syncthreads();

    // bias + residual
    const int c = t & 127, ng = t >> 7;
    float accv[8];
    const float bov = bo[c];
    #pragma unroll
    for (int i = 0; i < 8; i++){
        const int nn = ng*8 + i;
        const float v = lnb[nn*129 + c] + bov + x[(size_t)c*1024 + n0 + nn];
        accv[i] = v;
        lnb[nn*129 + c] = v;
    }
    __syncthreads();

    // LN stats: wave w owns rows w*4 .. w*4+3
    for (int r = w*4; r < w*4 + 4; r++){
        const float v0 = lnb[r*129 + l];
        const float v1 = lnb[r*129 + 64 + l];
        const float s  = wave_sum64(v0 + v1);
        const float qq = wave_sum64(fmaf(v0, v0, v1*v1));
        if (l == 0){
            const float mu  = s * 0.0078125f;
            const float var = qq * 0.0078125f - mu*mu;
            stats[r]      = mu;
            stats[16 + r] = rsqrtf(var + 1e-5f);
        }
    }
    __syncthreads();

    const float gm = gamma[c], bt = beta[c];
    float tmp[8];
    #pragma unroll
    for (int i = 0; i < 8; i++){
        const int nn = ng*8 + i;
        tmp[i] = (accv[i] - stats[nn]) * stats[16 + nn] * gm + bt;
    }
    float4* dst = (float4*)&out[(size_t)c*1024 + n0 + ng*8];
    dst[0] = make_float4(tmp[0], tmp[1], tmp[2], tmp[3]);
    dst[1] = make_float4(tmp[4], tmp[5], tmp[6], tmp[7]);
}

extern "C" void kernel_launch(void* const* d_in, const int* in_sizes, int n_in,
                              void* d_out, int out_size, void* d_ws, size_t ws_size,
                              hipStream_t stream)
{
    const float* x     = (const float*)d_in[0];
    const float* xyz   = (const float*)d_in[1];
    const float* Wq    = (const float*)d_in[2];
    const float* Wk    = (const float*)d_in[3];
    const float* Wv    = (const float*)d_in[4];
    const float* Wp1   = (const float*)d_in[5];
    const float* bp1   = (const float*)d_in[6];
    const float* Wp2   = (const float*)d_in[7];
    const float* bp2   = (const float*)d_in[8];
    const float* Wo    = (const float*)d_in[9];
    const float* bo    = (const float*)d_in[10];
    const float* gamma = (const float*)d_in[11];
    const float* beta  = (const float*)d_in[12];
    float* ws  = (float*)d_ws;
    float* out = (float*)d_out;

    hipLaunchKernelGGL(k_prep,  dim3(64, 2), dim3(256), 0, stream,
                       x, xyz, Wq, Wk, Wv, Wp1, bp1, Wp2, bp2, Wo, ws);
    hipLaunchKernelGGL(k_attn,  dim3(64, 8), dim3(256), 0, stream, ws, ws);
    hipLaunchKernelGGL(k_final, dim3(64),    dim3(256), 0, stream,
                       bo, x, gamma, beta, ws, out);
}

// Round 9
// 28.242 us; speedup vs baseline: 1.2522x; 1.2522x over previous
//
#include <hip/hip_runtime.h>
#include <hip/hip_bf16.h>

#define LOG2E 1.44269504088896340736f
#define C2G   0.39894228040143267794f   // 1/sqrt(2*pi)
#define K2M  -0.79788456080286535588f   // -2*C2G

typedef __attribute__((ext_vector_type(4))) float f32x4;
typedef __attribute__((ext_vector_type(8))) short s16x8;
typedef __attribute__((ext_vector_type(4))) short s16x4;

// ---------------- workspace layout (float offsets) ----------------
static constexpr size_t QF_OFF   = 0;        // [4h][64nt][2s][64l][8j] bf16
static constexpr size_t KF_OFF   = 131072;   // same shape (m-tiles)
static constexpr size_t VF_OFF   = 262144;   // [32ks][8tc][64l][8j] bf16
static constexpr size_t PACC_OFF = 327680;   // [8 chunk][1024 n][128 c] fp32
static constexpr size_t PMAX_OFF = 1376256;  // [8][4][1024]
static constexpr size_t PSUM_OFF = 1409024;  // [8][4][1024]
// total = 1,441,792 floats = 5.5 MB

__device__ __forceinline__ short f2bfs(float f){
    __hip_bfloat16 h = __float2bfloat16(f);
    return __builtin_bit_cast(short, h);
}
__device__ __forceinline__ float bf2f(unsigned short u){
    return __builtin_bit_cast(float, ((unsigned)u) << 16);
}
__device__ __forceinline__ float wave_sum64(float v){
    #pragma unroll
    for (int m = 32; m >= 1; m >>= 1) v += __shfl_xor(v, m, 64);
    return v;
}

// ---------------- kernel 1: projections + pos terms -> bf16 fragments ----
// grid (64, 4), block 512: x = n-tile of 16, y = mat (0=Q,1=K,2=V,3=pos).
// k-loop split across wave-halves (waves 0-3: k<64, waves 4-7: k>=64).
// Fragment k-bijections (HW-validated R5-R7):
//   scores g(l,j) = (l>>4)*8 + j ; PV f(l,j) = (l>>4)*4 + (j&3) + 16*(j>>2)
__global__ __launch_bounds__(512) void k_prep(
    const float* __restrict__ x, const float* __restrict__ xyz,
    const float* __restrict__ Wq, const float* __restrict__ Wk,
    const float* __restrict__ Wv, const float* __restrict__ Wp1,
    const float* __restrict__ bp1, const float* __restrict__ Wp2,
    const float* __restrict__ bp2, float* __restrict__ ws)
{
    __shared__ ushort wbf[128*130];   // W bf16 [c][k] pitch 130 (33KB)
    __shared__ float  xlds[128*16];   // x [k][n16] (8KB)
    __shared__ float  st0[128*17];    // half-sum kh=0 [c][nn] (mat3: pt)
    __shared__ float  st1[128*17];    // half-sum kh=1 (mat3: scratch)
    const int t   = threadIdx.x;
    const int mat = blockIdx.y;
    const int bx  = blockIdx.x;
    const int n0  = bx * 16;
    const int l = t & 63, w = t >> 6, g = l >> 4, col = l & 15;

    if (mat == 3){
        float* pt   = st0;            // [128][17]
        float* wb   = st1;            // [4][128]
        float* Msh  = st1 + 512;      // [4][9]
        float* bbar = st1 + 548;      // [4]
        float* kg   = st1 + 552;      // [4][3][16]
        float* rowt = st1 + 744;      // [4][16]
        float* colt = st1 + 808;      // [4][16]

        {   // wb: 512 threads -> one (h,c) each
            const int h = t >> 7, c = t & 127;
            float s = 0.f;
            #pragma unroll 8
            for (int d = 0; d < 32; d++) s += Wp2[(size_t)(h*32+d)*128 + c];
            wb[t] = s * 0.03125f;
        }
        if (t < 4){
            float s = 0.f;
            #pragma unroll 8
            for (int d = 0; d < 32; d++) s += bp2[t*32+d];
            bbar[t] = s * 0.03125f;
        }
        {   // p-tile: 4 n per thread
            const int c = t & 127, ng = t >> 7;
            const float w0 = Wp1[c*3], w1 = Wp1[c*3+1], w2 = Wp1[c*3+2];
            #pragma unroll
            for (int i = 0; i < 4; i++){
                const int nn = ng*4 + i, n = n0 + nn;
                pt[c*17 + nn] = w0*xyz[n*3] + w1*xyz[n*3+1] + w2*xyz[n*3+2];
            }
        }
        __syncthreads();

        if (t < 36){   // M_h[a][b] = sum_c wbar * Wp1[c,a] * Wp1[c,b]
            const int h = t / 9, ab = t % 9, a = ab / 3, b = ab % 3;
            float m = 0.f;
            for (int c = 0; c < 128; c++)
                m += wb[h*128+c] * Wp1[c*3+a] * Wp1[c*3+b];
            Msh[t] = m;
        }
        __syncthreads();

        if (t < 64){   // ROWT / COLT
            const int h = t >> 4, nn = t & 15;
            float ra = 0.f, ca = 0.f;
            for (int c = 0; c < 128; c++){
                const float wv = wb[h*128+c];
                const float p  = pt[c*17+nn];
                const float b1 = bp1[c];
                const float a  = fmaf(2.f*C2G, b1, 0.5f);
                const float p2 = C2G*p*p;
                ra += wv * (a*p + p2 + 0.5f*b1 + C2G*b1*b1);
                ca += wv * (p2 - a*p);
            }
            rowt[h*16+nn] = ra + bbar[h];
            colt[h*16+nn] = ca;
        } else if (t < 64 + 192){   // kg[h][a][nn]
            const int u = t - 64;
            const int nn = u & 15, ha = u >> 4, h = ha / 3, a = ha % 3;
            const int n = n0 + nn;
            const float gv = Msh[h*9+a*3+0]*xyz[n*3+0]
                           + Msh[h*9+a*3+1]*xyz[n*3+1]
                           + Msh[h*9+a*3+2]*xyz[n*3+2];
            kg[(h*3+a)*16 + nn] = K2M * gv;
        }
        __syncthreads();

        // bias fragments (s=1): 8 slots, one per wave (w = 0..7)
        {
            const int  sl  = w;
            const bool isQ = sl < 4;
            const int  h   = sl & 3;
            s16x8 v;
            #pragma unroll
            for (int j = 0; j < 8; j++){
                const int dd = g*8 + j;
                float f;
                if (isQ)
                    f = (dd < 3)  ? kg[(h*3+dd)*16 + col]
                      : (dd == 3) ? rowt[h*16 + col]
                      : (dd == 4) ? 1.0f : 0.0f;
                else
                    f = (dd < 3)  ? xyz[(size_t)(n0+col)*3 + dd]
                      : (dd == 3) ? 1.0f
                      : (dd == 4) ? colt[h*16 + col] : 0.0f;
                v[j] = f2bfs(f);
            }
            ((s16x8*)(ws + (isQ ? QF_OFF : KF_OFF)))[(size_t)(h*128 + bx*2 + 1)*64 + l] = v;
        }
        return;
    }

    // ---- mats 0..2: split-k GEMM tile + fragment emit ----
    const float* W = (mat == 0) ? Wq : (mat == 1 ? Wk : Wv);
    for (int i = t; i < 16384; i += 512)
        wbf[(i>>7)*130 + (i&127)] = (ushort)f2bfs(W[i]);
    for (int i = t; i < 2048; i += 512)
        xlds[i] = x[(size_t)(i>>4)*1024 + n0 + (i&15)];
    __syncthreads();

    const int c = t & 127, ng = (t >> 7) & 1, kh = t >> 8;
    float acc[8] = {0,0,0,0,0,0,0,0};
    const int kbase = kh*64;
    #pragma unroll 4
    for (int kk = 0; kk < 64; kk++){
        const int k = kbase + kk;
        const float wv = bf2f(wbf[c*130 + k]);
        const float4 a0 = *(const float4*)&xlds[k*16 + ng*8];
        const float4 a1 = *(const float4*)&xlds[k*16 + ng*8 + 4];
        acc[0] = fmaf(wv, a0.x, acc[0]);
        acc[1] = fmaf(wv, a0.y, acc[1]);
        acc[2] = fmaf(wv, a0.z, acc[2]);
        acc[3] = fmaf(wv, a0.w, acc[3]);
        acc[4] = fmaf(wv, a1.x, acc[4]);
        acc[5] = fmaf(wv, a1.y, acc[5]);
        acc[6] = fmaf(wv, a1.z, acc[6]);
        acc[7] = fmaf(wv, a1.w, acc[7]);
    }
    float* stg = kh ? st1 : st0;
    #pragma unroll
    for (int i = 0; i < 8; i++)
        stg[c*17 + ng*8 + i] = acc[i];
    __syncthreads();

    if (w < 4){   // emission by waves 0-3 (sum the two k-halves)
        const float qs = (mat == 0) ? 0.17677669529663689f : 1.0f;  // 1/sqrt(32)
        if (mat != 2){   // Q/K s=0 fragment: wave = head
            s16x8 v;
            #pragma unroll
            for (int j = 0; j < 8; j++){
                const int idx = (w*32 + g*8 + j)*17 + col;
                v[j] = f2bfs((st0[idx] + st1[idx]) * qs);
            }
            ((s16x8*)(ws + (mat == 0 ? QF_OFF : KF_OFF)))[(size_t)(w*128 + bx*2 + 0)*64 + l] = v;
        } else {         // V half-fragments: this block = m-tile bx
            #pragma unroll
            for (int q = 0; q < 2; q++){
                const int tc = w*2 + q;
                s16x4 hv;
                #pragma unroll
                for (int jj = 0; jj < 4; jj++){
                    const int idx = (tc*16 + col)*17 + g*4 + jj;
                    hv[jj] = f2bfs(st0[idx] + st1[idx]);
                }
                ((s16x4*)(ws + VF_OFF))[(((size_t)(bx>>1)*8 + tc)*64 + l)*2 + (bx & 1)] = hv;
            }
        }
    }
}

// ---------------- kernel 2: MFMA scores + chunk softmax + MFMA PV --------
// grid (64, 8): x = n-tile of 16, y = m-chunk of 128. block 256 = 4 waves,
// wave = head. No LDS. Wave h owns PV channels tc = 2h, 2h+1. (verbatim R7)
__global__ __launch_bounds__(256) void k_attn(
    const float* __restrict__ ws_c, float* __restrict__ ws)
{
    const int t = threadIdx.x, l = t & 63, h = t >> 6;
    const int bx = blockIdx.x, by = blockIdx.y;
    const int g = l >> 4;

    const s16x8* QFv = (const s16x8*)(ws_c + QF_OFF);
    const s16x8* KFv = (const s16x8*)(ws_c + KF_OFF);
    const s16x8* VFv = (const s16x8*)(ws_c + VF_OFF);

    const s16x8 bq0 = QFv[(size_t)(h*128 + bx*2 + 0)*64 + l];
    const s16x8 bq1 = QFv[(size_t)(h*128 + bx*2 + 1)*64 + l];

    f32x4 sc[8];
    #pragma unroll
    for (int tt = 0; tt < 8; tt++){
        const int mt = by*8 + tt;
        const s16x8 ak0 = KFv[(size_t)(h*128 + mt*2 + 0)*64 + l];
        const s16x8 ak1 = KFv[(size_t)(h*128 + mt*2 + 1)*64 + l];
        f32x4 c = {0.f,0.f,0.f,0.f};
        c = __builtin_amdgcn_mfma_f32_16x16x32_bf16(ak0, bq0, c, 0, 0, 0);
        c = __builtin_amdgcn_mfma_f32_16x16x32_bf16(ak1, bq1, c, 0, 0, 0);
        sc[tt] = c;
    }

    float mx = -3.4e38f;
    #pragma unroll
    for (int tt = 0; tt < 8; tt++)
        #pragma unroll
        for (int r = 0; r < 4; r++) mx = fmaxf(mx, sc[tt][r]);
    mx = fmaxf(mx, __shfl_xor(mx, 16, 64));
    mx = fmaxf(mx, __shfl_xor(mx, 32, 64));

    float sum = 0.f;
    #pragma unroll
    for (int tt = 0; tt < 8; tt++)
        #pragma unroll
        for (int r = 0; r < 4; r++){
            const float e = __builtin_amdgcn_exp2f((sc[tt][r] - mx)*LOG2E);
            sc[tt][r] = e;
            sum += e;
        }
    sum += __shfl_xor(sum, 16, 64);
    sum += __shfl_xor(sum, 32, 64);

    if (l < 16){
        ws[PMAX_OFF + (size_t)(by*4 + h)*1024 + bx*16 + l] = mx;
        ws[PSUM_OFF + (size_t)(by*4 + h)*1024 + bx*16 + l] = sum;
    }

    s16x8 pb[4];
    #pragma unroll
    for (int s = 0; s < 4; s++){
        s16x8 b;
        #pragma unroll
        for (int r = 0; r < 4; r++){
            b[r]   = f2bfs(sc[2*s][r]);
            b[4+r] = f2bfs(sc[2*s+1][r]);
        }
        pb[s] = b;
    }

    f32x4 o0 = {0.f,0.f,0.f,0.f}, o1 = {0.f,0.f,0.f,0.f};
    #pragma unroll
    for (int s = 0; s < 4; s++){
        const s16x8 av0 = VFv[(size_t)((by*4 + s)*8 + 2*h    )*64 + l];
        const s16x8 av1 = VFv[(size_t)((by*4 + s)*8 + 2*h + 1)*64 + l];
        o0 = __builtin_amdgcn_mfma_f32_16x16x32_bf16(av0, pb[s], o0, 0, 0, 0);
        o1 = __builtin_amdgcn_mfma_f32_16x16x32_bf16(av1, pb[s], o1, 0, 0, 0);
    }
    const size_t base = PACC_OFF + (size_t)(by*1024 + bx*16 + (l & 15))*128;
    *(f32x4*)&ws[base + (2*h    )*16 + g*4] = o0;
    *(f32x4*)&ws[base + (2*h + 1)*16 + g*4] = o1;
}

// ---------------- kernel 3: combine + Wo matmul + residual + LayerNorm ---
// grid (256), block 512: n-tile of 4, k-loop split across wave-halves.
__global__ __launch_bounds__(512) void k_final(
    const float* __restrict__ Wo, const float* __restrict__ bo,
    const float* __restrict__ x, const float* __restrict__ gamma,
    const float* __restrict__ beta, const float* __restrict__ ws,
    float* __restrict__ out)
{
    __shared__ ushort wbf[128*130];   // Wo bf16 [c][k] pitch 130 (33KB)
    __shared__ float alds[128*4];     // [k][nn] then reused as [nn][c]
    __shared__ float redb[2*128*4];   // [kh][c][nn]
    __shared__ float wcomb[8*16];     // [chunk][h*4+nn]
    __shared__ float stats[8];        // mu[4], rstd[4]
    const int t  = threadIdx.x;
    const int n0 = blockIdx.x * 4;

    for (int i = t; i < 16384; i += 512)
        wbf[(i>>7)*130 + (i&127)] = (ushort)f2bfs(Wo[i]);
    if (t < 16){   // combine weights per (h, nn)
        const int h = t >> 2, nn = t & 3;
        float pm[8]; float mx = -3.4e38f;
        #pragma unroll
        for (int k = 0; k < 8; k++){
            pm[k] = ws[PMAX_OFF + (size_t)(k*4 + h)*1024 + n0 + nn];
            mx = fmaxf(mx, pm[k]);
        }
        float lam[8]; float den = 0.f;
        #pragma unroll
        for (int k = 0; k < 8; k++){
            lam[k] = __builtin_amdgcn_exp2f((pm[k] - mx)*LOG2E);
            den = fmaf(lam[k], ws[PSUM_OFF + (size_t)(k*4 + h)*1024 + n0 + nn], den);
        }
        const float rd = __builtin_amdgcn_rcpf(den);
        #pragma unroll
        for (int k = 0; k < 8; k++) wcomb[k*16 + t] = lam[k]*rd;
    }
    __syncthreads();

    {   // combine PACC -> alds: 512 threads, one (c, nn) each
        const int c = t & 127, nn = t >> 7, h = c >> 5;
        float num = 0.f;
        #pragma unroll
        for (int k = 0; k < 8; k++)
            num = fmaf(wcomb[k*16 + h*4 + nn],
                       ws[PACC_OFF + (size_t)(k*1024 + n0 + nn)*128 + c], num);
        alds[c*4 + nn] = num;
    }
    __syncthreads();

    // split-k Wo GEMM: thread (c, q, kh); nn = q*2+{0,1}
    const int c = t & 127, q = (t >> 7) & 1, kh = t >> 8;
    float acc2[2] = {0.f, 0.f};
    const int kbase = kh*64;
    #pragma unroll 4
    for (int kk = 0; kk < 64; kk++){
        const int k = kbase + kk;
        const float  wv = bf2f(wbf[c*130 + k]);
        const float2 a2 = *(const float2*)&alds[k*4 + q*2];
        acc2[0] = fmaf(wv, a2.x, acc2[0]);
        acc2[1] = fmaf(wv, a2.y, acc2[1]);
    }
    redb[(kh*128 + c)*4 + q*2 + 0] = acc2[0];
    redb[(kh*128 + c)*4 + q*2 + 1] = acc2[1];
    __syncthreads();

    // reduce halves + bias + residual (threads 0..255: one (c, q) pair)
    float accv[2];
    if (t < 256){
        const int cc = t & 127, qq = t >> 7;
        const float bov = bo[cc];
        #pragma unroll
        for (int r = 0; r < 2; r++){
            const int nn = qq*2 + r;
            const float v = redb[(0*128 + cc)*4 + nn] + redb[(128 + cc)*4 + nn]
                          + bov + x[(size_t)cc*1024 + n0 + nn];
            accv[r] = v;
            alds[nn*128 + cc] = v;   // lnb [nn][c]
        }
    }
    __syncthreads();

    {   // LN stats: waves 0-3, wave w owns row w
        const int lane = t & 63, w = t >> 6;
        if (w < 4){
            const float v0 = alds[w*128 + lane];
            const float v1 = alds[w*128 + 64 + lane];
            const float s  = wave_sum64(v0 + v1);
            const float qq2 = wave_sum64(fmaf(v0, v0, v1*v1));
            if (lane == 0){
                const float mu  = s * 0.0078125f;
                const float var = qq2 * 0.0078125f - mu*mu;
                stats[w]     = mu;
                stats[4 + w] = rsqrtf(var + 1e-5f);
            }
        }
    }
    __syncthreads();

    if (t < 256){
        const int cc = t & 127, qq = t >> 7;
        const float g = gamma[cc], b = beta[cc];
        const int nn0 = qq*2;
        float2 o2;
        o2.x = (accv[0] - stats[nn0])   * stats[4 + nn0]   * g + b;
        o2.y = (accv[1] - stats[nn0+1]) * stats[4 + nn0+1] * g + b;
        *(float2*)(out + (size_t)cc*1024 + n0 + nn0) = o2;
    }
}

extern "C" void kernel_launch(void* const* d_in, const int* in_sizes, int n_in,
                              void* d_out, int out_size, void* d_ws, size_t ws_size,
                              hipStream_t stream)
{
    const float* x     = (const float*)d_in[0];
    const float* xyz   = (const float*)d_in[1];
    const float* Wq    = (const float*)d_in[2];
    const float* Wk    = (const float*)d_in[3];
    const float* Wv    = (const float*)d_in[4];
    const float* Wp1   = (const float*)d_in[5];
    const float* bp1   = (const float*)d_in[6];
    const float* Wp2   = (const float*)d_in[7];
    const float* bp2   = (const float*)d_in[8];
    const float* Wo    = (const float*)d_in[9];
    const float* bo    = (const float*)d_in[10];
    const float* gamma = (const float*)d_in[11];
    const float* beta  = (const float*)d_in[12];
    float* ws  = (float*)d_ws;
    float* out = (float*)d_out;

    hipLaunchKernelGGL(k_prep,  dim3(64, 4), dim3(512), 0, stream,
                       x, xyz, Wq, Wk, Wv, Wp1, bp1, Wp2, bp2, ws);
    hipLaunchKernelGGL(k_attn,  dim3(64, 8), dim3(256), 0, stream, ws, ws);
    hipLaunchKernelGGL(k_final, dim3(256),   dim3(512), 0, stream,
                       Wo, bo, x, gamma, beta, ws, out);
}